// Round 4
// baseline (639.676 us; speedup 1.0000x reference)
//
#include <hip/hip_runtime.h>
#include <math.h>

// Round 4: GEMM LDS xor-swizzle (kill 8-way frag-read bank conflicts) +
// transposed accumulator (vectorized epilogue). Flash: scale folded into Q.
//
// Pipeline:
//   wT_*  = transpose+f16(w_*)                   [wconv x4]
//   lnbuf = LN(x, ln1) -> f16                    [ln_kernel]
//   qk,vT = lnbuf @ wT_attn + b_attn             [gemm_f16<3>]
//   ybuf  = mfma_flash(qk, vT) -> f16            [flash_kernel]
//   out   = ybuf @ wT_proj + b_proj + x          [gemm_f16<1>]
//   lnbuf = LN(out, ln2) -> f16                  [ln_kernel]
//   h     = gelu(lnbuf @ wT_fc + b_fc) -> f16    [gemm_f16<2>]
//   out   = h @ wT_fc2 + b_fc2 + out             [gemm_f16<1>]
//
// ws: [0,16M) lnbuf | [16,48M) qk | [48,64M) vT | [64,80M) ybuf
//     [80,144M) h | [144,170M) wT

#define M_ROWS 8192
#define T_SEQ 2048
#define N_EMB 1024
#define N_HEADS 16
#define HEAD_D 64

typedef _Float16 f16;
typedef __attribute__((ext_vector_type(8))) _Float16 f16x8;
typedef __attribute__((ext_vector_type(4))) _Float16 f16x4;
typedef __attribute__((ext_vector_type(4))) float f32x4;

__device__ __forceinline__ void async16(void* lds, const void* g) {
    __builtin_amdgcn_global_load_lds(
        (const __attribute__((address_space(1))) unsigned int*)g,
        (__attribute__((address_space(3))) unsigned int*)lds, 16, 0, 0);
}

__device__ __forceinline__ float gelu_tanh(float v) {
    float u = 0.7978845608028654f * (v + 0.044715f * v * v * v);
    float e = __expf(2.0f * u);
    float t = 1.0f - 2.0f / (e + 1.0f);
    return 0.5f * v * (1.0f + t);
}

// ---------------------------------------------------------------- weight convert
__launch_bounds__(256)
__global__ void wconv_kernel(const float* __restrict__ W, f16* __restrict__ WT,
                             int K, int N) {
    __shared__ float t[32][33];
    int tx = threadIdx.x & 31, ty = threadIdx.x >> 5;
    int n0 = blockIdx.x * 32, k0 = blockIdx.y * 32;
    #pragma unroll
    for (int r = 0; r < 4; r++)
        t[ty * 4 + r][tx] = W[(size_t)(k0 + ty * 4 + r) * N + n0 + tx];
    __syncthreads();
    #pragma unroll
    for (int r = 0; r < 4; r++)
        WT[(size_t)(n0 + ty * 4 + r) * K + k0 + tx] = (f16)t[tx][ty * 4 + r];
}

// ---------------------------------------------------------------- LayerNorm -> f16
__launch_bounds__(256)
__global__ void ln_kernel(const float* __restrict__ x, const float* __restrict__ g,
                          const float* __restrict__ b, f16* __restrict__ y) {
    int row = blockIdx.x;
    int tid = threadIdx.x;
    const float* xr = x + (size_t)row * N_EMB;
    float4 v = *(const float4*)(xr + tid * 4);
    float s  = v.x + v.y + v.z + v.w;
    float sq = v.x * v.x + v.y * v.y + v.z * v.z + v.w * v.w;
    #pragma unroll
    for (int off = 32; off > 0; off >>= 1) {
        s  += __shfl_down(s, off);
        sq += __shfl_down(sq, off);
    }
    __shared__ float ws_[4], wq_[4];
    __shared__ float mean_s, rstd_s;
    int lane = tid & 63, wid = tid >> 6;
    if (lane == 0) { ws_[wid] = s; wq_[wid] = sq; }
    __syncthreads();
    if (tid == 0) {
        float st = ws_[0] + ws_[1] + ws_[2] + ws_[3];
        float qt = wq_[0] + wq_[1] + wq_[2] + wq_[3];
        float mu = st * (1.0f / N_EMB);
        float var = qt * (1.0f / N_EMB) - mu * mu;
        mean_s = mu;
        rstd_s = rsqrtf(var + 1e-5f);
    }
    __syncthreads();
    float mu = mean_s, r = rstd_s;
    float4 gv = *(const float4*)(g + tid * 4);
    float4 bv = *(const float4*)(b + tid * 4);
    f16x4 o;
    o.x = (f16)((v.x - mu) * r * gv.x + bv.x);
    o.y = (f16)((v.y - mu) * r * gv.y + bv.y);
    o.z = (f16)((v.z - mu) * r * gv.z + bv.z);
    o.w = (f16)((v.w - mu) * r * gv.w + bv.w);
    *(f16x4*)(y + (size_t)row * N_EMB + tid * 4) = o;
}

// ---------------------------------------------------------------- GEMM f16 MFMA
// 128x128 tile, BK=32, 4 waves (2x2 of 64x64), 4x4 MFMA grid.
// LDS xor-swizzle: slot (row,g) holds global seg g ^ r2(row),
// r2(row) = (row&3)^((row>>2)&3) -> frag reads are 2-way (free).
// TRANSPOSED accumulator: acc = mfma(B-frag, A-frag) so each lane owns
// 4 consecutive output COLUMNS at one row -> vectorized epilogue.
// EPI: 0 f32 | 1 f32 + f32 residual | 2 gelu->f16 | 3 qkv split
template <int EPI>
__launch_bounds__(256)
__global__ void gemm_f16(const f16* __restrict__ A, const f16* __restrict__ Bt,
                         const float* __restrict__ bias, const float* __restrict__ res,
                         float* __restrict__ Cf, f16* __restrict__ Ch,
                         f16* __restrict__ vT, int K, int N) {
    __shared__ f16 As[128 * 32];
    __shared__ f16 Bs[128 * 32];
    int tid = threadIdx.x;
    int lane = tid & 63, wave = tid >> 6;
    int wr = wave >> 1, wc = wave & 1;
    int quad = lane >> 4, l16 = lane & 15;
    int m0 = blockIdx.y * 128, n0 = blockIdx.x * 128;

    f32x4 acc[4][4] = {};

    // staging swizzle (lane-constant): slot (row,seg) fetches global seg s
    int srowA[2], ssegA[2];
    #pragma unroll
    for (int i = 0; i < 2; i++) {
        int L = i * 256 + tid;
        int row = L >> 2, seg = L & 3;
        srowA[i] = row;
        ssegA[i] = seg ^ (row & 3) ^ ((row >> 2) & 3);
    }
    // frag-read swizzle term (lane-constant)
    int r2 = (l16 & 3) ^ (l16 >> 2);

    for (int k0 = 0; k0 < K; k0 += 32) {
        #pragma unroll
        for (int i = 0; i < 2; i++) {
            int L = i * 256 + tid;
            async16((char*)As + (size_t)L * 16,
                    A + (size_t)(m0 + srowA[i]) * K + k0 + ssegA[i] * 8);
        }
        #pragma unroll
        for (int i = 0; i < 2; i++) {
            int L = i * 256 + tid;
            async16((char*)Bs + (size_t)L * 16,
                    Bt + (size_t)(n0 + srowA[i]) * K + k0 + ssegA[i] * 8);
        }
        __syncthreads();

        f16x8 af[4], bf[4];
        #pragma unroll
        for (int i = 0; i < 4; i++)
            af[i] = *(const f16x8*)&As[(size_t)((wr * 64 + i * 16 + l16) * 4 +
                                                (quad ^ r2)) * 8];
        #pragma unroll
        for (int j = 0; j < 4; j++)
            bf[j] = *(const f16x8*)&Bs[(size_t)((wc * 64 + j * 16 + l16) * 4 +
                                                (quad ^ r2)) * 8];
        #pragma unroll
        for (int i = 0; i < 4; i++)
            #pragma unroll
            for (int j = 0; j < 4; j++)
                acc[i][j] = __builtin_amdgcn_mfma_f32_16x16x32_f16(
                    bf[j], af[i], acc[i][j], 0, 0, 0);   // transposed: D[n][m]
        __syncthreads();
    }

    // epilogue: lane owns row m (fixed), 4 consecutive cols per (i,j)
    #pragma unroll
    for (int i = 0; i < 4; i++) {
        int m = m0 + wr * 64 + i * 16 + l16;
        #pragma unroll
        for (int j = 0; j < 4; j++) {
            int nb = n0 + wc * 64 + j * 16 + quad * 4;
            float4 bb = *(const float4*)(bias + nb);
            float v0 = acc[i][j][0] + bb.x;
            float v1 = acc[i][j][1] + bb.y;
            float v2 = acc[i][j][2] + bb.z;
            float v3 = acc[i][j][3] + bb.w;
            if (EPI == 3) {
                if (n0 < 2048) {
                    f16x4 pk = {(f16)v0, (f16)v1, (f16)v2, (f16)v3};
                    *(f16x4*)(Ch + (size_t)m * 2048 + nb) = pk;
                } else {
                    int hh = (nb - 2048) >> 6, d0 = nb & 63;
                    int b_ = m >> 11, t0 = m & 2047;
                    f16* vbase = vT + ((size_t)(b_ * 16 + hh) * 64 + d0) * 2048 + t0;
                    vbase[0]        = (f16)v0;
                    vbase[2048]     = (f16)v1;
                    vbase[2 * 2048] = (f16)v2;
                    vbase[3 * 2048] = (f16)v3;
                }
            } else if (EPI == 2) {
                f16x4 pk = {(f16)gelu_tanh(v0), (f16)gelu_tanh(v1),
                            (f16)gelu_tanh(v2), (f16)gelu_tanh(v3)};
                *(f16x4*)(Ch + (size_t)m * N + nb) = pk;
            } else {
                size_t idx = (size_t)m * N + nb;
                if (EPI == 1) {
                    float4 rr = *(const float4*)(res + idx);
                    v0 += rr.x; v1 += rr.y; v2 += rr.z; v3 += rr.w;
                }
                float4 ov = {v0, v1, v2, v3};
                *(float4*)(Cf + idx) = ov;
            }
        }
    }
}

// ---------------------------------------------------------------- MFMA flash
// 256 thr = 4 waves; 128 q-rows/block (wave w owns 32), 128-wide j-tiles.
// S^T = K.Q^T (C-layout: 4 consecutive j per lane). Q pre-scaled by 1/8.
__launch_bounds__(256, 2)
__global__ void flash_kernel(const f16* __restrict__ qk, const f16* __restrict__ vT,
                             f16* __restrict__ y) {
    __shared__ __align__(16) char smem[67584];
    f16* Ks = (f16*)smem;                      // [128 j][8 g of 8 d], g^=(j&7)
    f16* Vs = (f16*)(smem + 16384);            // [64 d][16 g of 8 j], g^=(d&7)
    int tid = threadIdx.x;
    int lane = tid & 63, w = tid >> 6;
    int quad = lane >> 4, l16 = lane & 15;
    f16* Ps = (f16*)(smem + 32768 + w * 8704); // per-wave [32 q][136 j]

    int qt = 15 - blockIdx.x;                  // long blocks first
    int bh = blockIdx.y;
    int b = bh >> 4, h = bh & 15;
    int q0 = qt * 128;

    // Q B-frags, pre-scaled by 1/sqrt(D)=0.125 (exact in f16)
    f16x8 qf[2][2];
    #pragma unroll
    for (int qn = 0; qn < 2; qn++) {
        int q = q0 + w * 32 + qn * 16 + l16;
        #pragma unroll
        for (int dblk = 0; dblk < 2; dblk++) {
            f16x8 t = *(const f16x8*)(qk + (size_t)(b * T_SEQ + q) * 2048 +
                                      h * 64 + dblk * 32 + quad * 8);
            #pragma unroll
            for (int e = 0; e < 8; e++) t[e] = t[e] * (f16)0.125f;
            qf[qn][dblk] = t;
        }
    }

    float m_r[2] = {-INFINITY, -INFINITY};
    float l_r[2] = {0.0f, 0.0f};
    f32x4 Oacc[2][4] = {};

    for (int jt = 0; jt <= qt; jt++) {
        int j0 = jt * 128;
        __syncthreads();
        #pragma unroll
        for (int i = 0; i < 4; i++) {
            int L = i * 256 + tid;
            int j = L >> 3, g1 = L & 7;
            int g = g1 ^ (j & 7);
            async16((char*)Ks + (size_t)L * 16,
                    qk + (size_t)(b * T_SEQ + j0 + j) * 2048 + 1024 + h * 64 + g * 8);
        }
        #pragma unroll
        for (int i = 0; i < 4; i++) {
            int L = i * 256 + tid;
            int d = L >> 4, g1 = L & 15;
            int g = (g1 & 8) | ((g1 ^ d) & 7);
            async16((char*)Vs + (size_t)L * 16,
                    vT + ((size_t)(bh) * 64 + d) * 2048 + j0 + g * 8);
        }
        __syncthreads();

        // S^T = K . Q^T (pre-scaled)
        f32x4 S[8][2];
        #pragma unroll
        for (int jm = 0; jm < 8; jm++) {
            f16x8 kf[2];
            #pragma unroll
            for (int dblk = 0; dblk < 2; dblk++) {
                int j = jm * 16 + l16;
                int g = (dblk * 4 + quad) ^ (j & 7);
                kf[dblk] = *(const f16x8*)(Ks + (size_t)(j * 8 + g) * 8);
            }
            #pragma unroll
            for (int qn = 0; qn < 2; qn++) {
                f32x4 s = {};
                s = __builtin_amdgcn_mfma_f32_16x16x32_f16(kf[0], qf[qn][0], s, 0, 0, 0);
                s = __builtin_amdgcn_mfma_f32_16x16x32_f16(kf[1], qf[qn][1], s, 0, 0, 0);
                S[jm][qn] = s;
            }
        }

        if (jt == qt) {
            #pragma unroll
            for (int jm = 0; jm < 8; jm++)
                #pragma unroll
                for (int qn = 0; qn < 2; qn++)
                    #pragma unroll
                    for (int r = 0; r < 4; r++) {
                        int jl = jm * 16 + quad * 4 + r;
                        int ql = w * 32 + qn * 16 + l16;
                        if (jl > ql) S[jm][qn][r] = -1e30f;
                    }
        }

        float alpha[2];
        #pragma unroll
        for (int qn = 0; qn < 2; qn++) {
            float tmax = -INFINITY;
            #pragma unroll
            for (int jm = 0; jm < 8; jm++)
                #pragma unroll
                for (int r = 0; r < 4; r++)
                    tmax = fmaxf(tmax, S[jm][qn][r]);
            tmax = fmaxf(tmax, __shfl_xor(tmax, 16));
            tmax = fmaxf(tmax, __shfl_xor(tmax, 32));
            float mnew = fmaxf(m_r[qn], tmax);
            alpha[qn] = __expf(m_r[qn] - mnew);
            m_r[qn] = mnew;
            float rsum = 0.0f;
            #pragma unroll
            for (int jm = 0; jm < 8; jm++)
                #pragma unroll
                for (int r = 0; r < 4; r++) {
                    float p = __expf(S[jm][qn][r] - mnew);
                    S[jm][qn][r] = p;
                    rsum += p;
                }
            rsum += __shfl_xor(rsum, 16);
            rsum += __shfl_xor(rsum, 32);
            l_r[qn] = l_r[qn] * alpha[qn] + rsum;
        }

        #pragma unroll
        for (int jm = 0; jm < 8; jm++)
            #pragma unroll
            for (int qn = 0; qn < 2; qn++) {
                f16x4 pk;
                pk.x = (f16)S[jm][qn][0];
                pk.y = (f16)S[jm][qn][1];
                pk.z = (f16)S[jm][qn][2];
                pk.w = (f16)S[jm][qn][3];
                *(f16x4*)(Ps + (size_t)(qn * 16 + l16) * 136 + jm * 16 + quad * 4) = pk;
            }

        float aPV[2][4];
        #pragma unroll
        for (int m = 0; m < 2; m++)
            #pragma unroll
            for (int r = 0; r < 4; r++)
                aPV[m][r] = __shfl(alpha[m], quad * 20 + r);
        #pragma unroll
        for (int m = 0; m < 2; m++)
            #pragma unroll
            for (int n = 0; n < 4; n++)
                #pragma unroll
                for (int r = 0; r < 4; r++)
                    Oacc[m][n][r] *= aPV[m][r];

        #pragma unroll
        for (int kblk = 0; kblk < 4; kblk++) {
            f16x8 pf[2];
            #pragma unroll
            for (int m = 0; m < 2; m++)
                pf[m] = *(const f16x8*)(Ps + (size_t)(m * 16 + l16) * 136 +
                                        kblk * 32 + quad * 8);
            f16x8 vf[4];
            #pragma unroll
            for (int n = 0; n < 4; n++) {
                int d = n * 16 + l16;
                int g = (kblk * 4 + quad);
                int gs = (g & 8) | ((g ^ d) & 7);
                vf[n] = *(const f16x8*)(Vs + (size_t)(d * 16 + gs) * 8);
            }
            #pragma unroll
            for (int m = 0; m < 2; m++)
                #pragma unroll
                for (int n = 0; n < 4; n++)
                    Oacc[m][n] = __builtin_amdgcn_mfma_f32_16x16x32_f16(
                        pf[m], vf[n], Oacc[m][n], 0, 0, 0);
        }
    }

    #pragma unroll
    for (int m = 0; m < 2; m++) {
        float lPV[4];
        #pragma unroll
        for (int r = 0; r < 4; r++)
            lPV[r] = 1.0f / __shfl(l_r[m], quad * 20 + r);
        #pragma unroll
        for (int n = 0; n < 4; n++) {
            #pragma unroll
            for (int r = 0; r < 4; r++) {
                int q = q0 + w * 32 + m * 16 + quad * 4 + r;
                y[(size_t)(b * T_SEQ + q) * N_EMB + h * 64 + n * 16 + l16] =
                    (f16)(Oacc[m][n][r] * lPV[r]);
            }
        }
    }
}

// ---------------------------------------------------------------- launch
extern "C" void kernel_launch(void* const* d_in, const int* in_sizes, int n_in,
                              void* d_out, int out_size, void* d_ws, size_t ws_size,
                              hipStream_t stream) {
    const float* x      = (const float*)d_in[0];
    const float* ln1_g  = (const float*)d_in[1];
    const float* ln1_b  = (const float*)d_in[2];
    const float* w_attn = (const float*)d_in[3];
    const float* b_attn = (const float*)d_in[4];
    const float* w_proj = (const float*)d_in[5];
    const float* b_proj = (const float*)d_in[6];
    const float* ln2_g  = (const float*)d_in[7];
    const float* ln2_b  = (const float*)d_in[8];
    const float* w_fc   = (const float*)d_in[9];
    const float* b_fc   = (const float*)d_in[10];
    const float* w_fc2  = (const float*)d_in[11];
    const float* b_fc2  = (const float*)d_in[12];
    float* out = (float*)d_out;

    const size_t MB = 1024 * 1024;
    char* ws = (char*)d_ws;
    f16*   lnbuf = (f16*)ws;                        // 16 MB
    f16*   qkbuf = (f16*)(ws + 16 * MB);            // 32 MB: [M][2048] Q|K
    f16*   vTbuf = (f16*)(ws + 48 * MB);            // 16 MB: [b][h][d][t]
    f16*   ybuf  = (f16*)(ws + 64 * MB);            // 16 MB
    f16*   h     = (f16*)(ws + 80 * MB);            // 64 MB
    f16*   wT    = (f16*)(ws + 144 * MB);           // 26 MB
    f16* wT_attn = wT;
    f16* wT_proj = wT_attn + (size_t)3072 * 1024;
    f16* wT_fc   = wT_proj + (size_t)1024 * 1024;
    f16* wT_fc2  = wT_fc   + (size_t)1024 * 4096;

    wconv_kernel<<<dim3(3072 / 32, 1024 / 32), 256, 0, stream>>>(w_attn, wT_attn, 1024, 3072);
    wconv_kernel<<<dim3(1024 / 32, 1024 / 32), 256, 0, stream>>>(w_proj, wT_proj, 1024, 1024);
    wconv_kernel<<<dim3(4096 / 32, 1024 / 32), 256, 0, stream>>>(w_fc,   wT_fc,   1024, 4096);
    wconv_kernel<<<dim3(1024 / 32, 4096 / 32), 256, 0, stream>>>(w_fc2,  wT_fc2,  4096, 1024);

    ln_kernel<<<M_ROWS, 256, 0, stream>>>(x, ln1_g, ln1_b, lnbuf);
    gemm_f16<3><<<dim3(3072 / 128, M_ROWS / 128), 256, 0, stream>>>(
        lnbuf, wT_attn, b_attn, nullptr, nullptr, qkbuf, vTbuf, 1024, 3072);
    flash_kernel<<<dim3(16, 64), 256, 0, stream>>>(qkbuf, vTbuf, ybuf);
    gemm_f16<1><<<dim3(1024 / 128, M_ROWS / 128), 256, 0, stream>>>(
        ybuf, wT_proj, b_proj, x, out, nullptr, nullptr, 1024, 1024);
    ln_kernel<<<M_ROWS, 256, 0, stream>>>(out, ln2_g, ln2_b, lnbuf);
    gemm_f16<2><<<dim3(4096 / 128, M_ROWS / 128), 256, 0, stream>>>(
        lnbuf, wT_fc, b_fc, nullptr, nullptr, h, nullptr, 1024, 4096);
    gemm_f16<1><<<dim3(1024 / 128, M_ROWS / 128), 256, 0, stream>>>(
        h, wT_fc2, b_fc2, out, out, nullptr, nullptr, 4096, 1024);
}

// Round 5
// 576.524 us; speedup vs baseline: 1.1095x; 1.1095x over previous
//
#include <hip/hip_runtime.h>
#include <math.h>

// Round 5: GEMM K-loop restructured — double-buffered LDS, ONE barrier per
// k-iter, DMA prefetch for tile k+1 issued before computing tile k (overlaps
// the vmcnt drain that stalled the 2-barrier m97 structure). Epilogue reverted
// to round-3 non-transposed form (vectorized V store). Flash unchanged.
//
// Pipeline:
//   wT_*  = transpose+f16(w_*)                   [wconv x4]
//   lnbuf = LN(x, ln1) -> f16                    [ln_kernel]
//   qk,vT = lnbuf @ wT_attn + b_attn             [gemm_f16<3>]
//   ybuf  = mfma_flash(qk, vT) -> f16            [flash_kernel]
//   out   = ybuf @ wT_proj + b_proj + x          [gemm_f16<1>]
//   lnbuf = LN(out, ln2) -> f16                  [ln_kernel]
//   h     = gelu(lnbuf @ wT_fc + b_fc) -> f16    [gemm_f16<2>]
//   out   = h @ wT_fc2 + b_fc2 + out             [gemm_f16<1>]
//
// ws: [0,16M) lnbuf | [16,48M) qk | [48,64M) vT | [64,80M) ybuf
//     [80,144M) h | [144,170M) wT

#define M_ROWS 8192
#define T_SEQ 2048
#define N_EMB 1024
#define N_HEADS 16
#define HEAD_D 64

typedef _Float16 f16;
typedef __attribute__((ext_vector_type(8))) _Float16 f16x8;
typedef __attribute__((ext_vector_type(4))) _Float16 f16x4;
typedef __attribute__((ext_vector_type(4))) float f32x4;

__device__ __forceinline__ void async16(void* lds, const void* g) {
    __builtin_amdgcn_global_load_lds(
        (const __attribute__((address_space(1))) unsigned int*)g,
        (__attribute__((address_space(3))) unsigned int*)lds, 16, 0, 0);
}

__device__ __forceinline__ float gelu_tanh(float v) {
    float u = 0.7978845608028654f * (v + 0.044715f * v * v * v);
    float e = __expf(2.0f * u);
    float t = 1.0f - 2.0f / (e + 1.0f);
    return 0.5f * v * (1.0f + t);
}

// ---------------------------------------------------------------- weight convert
__launch_bounds__(256)
__global__ void wconv_kernel(const float* __restrict__ W, f16* __restrict__ WT,
                             int K, int N) {
    __shared__ float t[32][33];
    int tx = threadIdx.x & 31, ty = threadIdx.x >> 5;
    int n0 = blockIdx.x * 32, k0 = blockIdx.y * 32;
    #pragma unroll
    for (int r = 0; r < 4; r++)
        t[ty * 4 + r][tx] = W[(size_t)(k0 + ty * 4 + r) * N + n0 + tx];
    __syncthreads();
    #pragma unroll
    for (int r = 0; r < 4; r++)
        WT[(size_t)(n0 + ty * 4 + r) * K + k0 + tx] = (f16)t[tx][ty * 4 + r];
}

// ---------------------------------------------------------------- LayerNorm -> f16
__launch_bounds__(256)
__global__ void ln_kernel(const float* __restrict__ x, const float* __restrict__ g,
                          const float* __restrict__ b, f16* __restrict__ y) {
    int row = blockIdx.x;
    int tid = threadIdx.x;
    const float* xr = x + (size_t)row * N_EMB;
    float4 v = *(const float4*)(xr + tid * 4);
    float s  = v.x + v.y + v.z + v.w;
    float sq = v.x * v.x + v.y * v.y + v.z * v.z + v.w * v.w;
    #pragma unroll
    for (int off = 32; off > 0; off >>= 1) {
        s  += __shfl_down(s, off);
        sq += __shfl_down(sq, off);
    }
    __shared__ float ws_[4], wq_[4];
    __shared__ float mean_s, rstd_s;
    int lane = tid & 63, wid = tid >> 6;
    if (lane == 0) { ws_[wid] = s; wq_[wid] = sq; }
    __syncthreads();
    if (tid == 0) {
        float st = ws_[0] + ws_[1] + ws_[2] + ws_[3];
        float qt = wq_[0] + wq_[1] + wq_[2] + wq_[3];
        float mu = st * (1.0f / N_EMB);
        float var = qt * (1.0f / N_EMB) - mu * mu;
        mean_s = mu;
        rstd_s = rsqrtf(var + 1e-5f);
    }
    __syncthreads();
    float mu = mean_s, r = rstd_s;
    float4 gv = *(const float4*)(g + tid * 4);
    float4 bv = *(const float4*)(b + tid * 4);
    f16x4 o;
    o.x = (f16)((v.x - mu) * r * gv.x + bv.x);
    o.y = (f16)((v.y - mu) * r * gv.y + bv.y);
    o.z = (f16)((v.z - mu) * r * gv.z + bv.z);
    o.w = (f16)((v.w - mu) * r * gv.w + bv.w);
    *(f16x4*)(y + (size_t)row * N_EMB + tid * 4) = o;
}

// ---------------------------------------------------------------- GEMM f16 MFMA
// 128x128 tile, BK=32, 4 waves (2x2 of 64x64), 4x4 MFMA grid, DOUBLE-buffered
// LDS with one barrier per k-iter:
//   stage(0); loop { barrier; prefetch(p^1); ds_read+MFMA(p); p^=1 }
// The prefetch DMA overlaps the whole compute phase instead of being drained
// cold at the barrier (the m97-structure stall).
// EPI: 0 f32 | 1 f32 + f32 residual | 2 gelu->f16 | 3 qkv split
template <int EPI>
__launch_bounds__(256)
__global__ void gemm_f16(const f16* __restrict__ A, const f16* __restrict__ Bt,
                         const float* __restrict__ bias, const float* __restrict__ res,
                         float* __restrict__ Cf, f16* __restrict__ Ch,
                         f16* __restrict__ vT, int K, int N) {
    __shared__ f16 As[2][128 * 32];
    __shared__ f16 Bs[2][128 * 32];
    int tid = threadIdx.x;
    int lane = tid & 63, wave = tid >> 6;
    int wr = wave >> 1, wc = wave & 1;
    int quad = lane >> 4, l16 = lane & 15;
    int m0 = blockIdx.y * 128, n0 = blockIdx.x * 128;

    // staging addresses (hoisted): thread covers LDS slots tid and 256+tid,
    // i.e. rows r0 and r0+64, 16B segment s0.
    int r0 = tid >> 2;
    int s0 = (tid & 3) * 8;
    const f16* paA0 = A  + (size_t)(m0 + r0) * K + s0;
    const f16* paA1 = A  + (size_t)(m0 + r0 + 64) * K + s0;
    const f16* paB0 = Bt + (size_t)(n0 + r0) * K + s0;
    const f16* paB1 = Bt + (size_t)(n0 + r0 + 64) * K + s0;
    char* dA0 = (char*)As + (size_t)tid * 16;
    char* dA1 = (char*)As + (size_t)(256 + tid) * 16;
    char* dB0 = (char*)Bs + (size_t)tid * 16;
    char* dB1 = (char*)Bs + (size_t)(256 + tid) * 16;

    // prologue: stage tile 0 into buffer 0
    async16(dA0, paA0);
    async16(dA1, paA1);
    async16(dB0, paB0);
    async16(dB1, paB1);

    f32x4 acc[4][4] = {};
    int p = 0;
    for (int k0 = 0; k0 < K; k0 += 32, p ^= 1) {
        __syncthreads();   // drains DMA into buf p; prior reads of buf p^1 done
        if (k0 + 32 < K) { // prefetch next tile into buf p^1 (overlaps compute)
            int koff = k0 + 32;
            async16(dA0 + (p ^ 1) * 8192, paA0 + koff);
            async16(dA1 + (p ^ 1) * 8192, paA1 + koff);
            async16(dB0 + (p ^ 1) * 8192, paB0 + koff);
            async16(dB1 + (p ^ 1) * 8192, paB1 + koff);
        }
        const f16* as = As[p];
        const f16* bs = Bs[p];
        f16x8 af[4], bf[4];
        #pragma unroll
        for (int i = 0; i < 4; i++)
            af[i] = *(const f16x8*)&as[(wr * 64 + i * 16 + l16) * 32 + quad * 8];
        #pragma unroll
        for (int j = 0; j < 4; j++)
            bf[j] = *(const f16x8*)&bs[(wc * 64 + j * 16 + l16) * 32 + quad * 8];
        #pragma unroll
        for (int i = 0; i < 4; i++)
            #pragma unroll
            for (int j = 0; j < 4; j++)
                acc[i][j] = __builtin_amdgcn_mfma_f32_16x16x32_f16(
                    af[i], bf[j], acc[i][j], 0, 0, 0);
    }

    // epilogue (round-3 form): C/D layout col=lane&15, row=quad*4+r
    #pragma unroll
    for (int i = 0; i < 4; i++) {
        int row0 = m0 + wr * 64 + i * 16 + quad * 4;
        #pragma unroll
        for (int j = 0; j < 4; j++) {
            int col = n0 + wc * 64 + j * 16 + l16;
            float bb = bias[col];
            if (EPI == 3) {
                if (n0 < 2048) {
                    #pragma unroll
                    for (int r = 0; r < 4; r++)
                        Ch[(size_t)(row0 + r) * 2048 + col] = (f16)(acc[i][j][r] + bb);
                } else {
                    int hh = (col - 2048) >> 6, dd = col & 63;
                    int bb_ = row0 >> 11, t0 = row0 & 2047;
                    f16x4 pk;
                    pk.x = (f16)(acc[i][j][0] + bb);
                    pk.y = (f16)(acc[i][j][1] + bb);
                    pk.z = (f16)(acc[i][j][2] + bb);
                    pk.w = (f16)(acc[i][j][3] + bb);
                    *(f16x4*)(vT + ((size_t)(bb_ * 16 + hh) * 64 + dd) * 2048 + t0) = pk;
                }
            } else {
                #pragma unroll
                for (int r = 0; r < 4; r++) {
                    size_t idx = (size_t)(row0 + r) * N + col;
                    float v = acc[i][j][r] + bb;
                    if (EPI == 1) v += res[idx];
                    if (EPI == 2) Ch[idx] = (f16)gelu_tanh(v);
                    else          Cf[idx] = v;
                }
            }
        }
    }
}

// ---------------------------------------------------------------- MFMA flash
// 256 thr = 4 waves; 128 q-rows/block (wave w owns 32), 128-wide j-tiles.
// S^T = K.Q^T (C-layout: 4 consecutive j per lane). Q pre-scaled by 1/8.
__launch_bounds__(256, 2)
__global__ void flash_kernel(const f16* __restrict__ qk, const f16* __restrict__ vT,
                             f16* __restrict__ y) {
    __shared__ __align__(16) char smem[67584];
    f16* Ks = (f16*)smem;                      // [128 j][8 g of 8 d], g^=(j&7)
    f16* Vs = (f16*)(smem + 16384);            // [64 d][16 g of 8 j], g^=(d&7)
    int tid = threadIdx.x;
    int lane = tid & 63, w = tid >> 6;
    int quad = lane >> 4, l16 = lane & 15;
    f16* Ps = (f16*)(smem + 32768 + w * 8704); // per-wave [32 q][136 j]

    int qt = 15 - blockIdx.x;                  // long blocks first
    int bh = blockIdx.y;
    int b = bh >> 4, h = bh & 15;
    int q0 = qt * 128;

    // Q B-frags, pre-scaled by 1/sqrt(D)=0.125 (exact in f16)
    f16x8 qf[2][2];
    #pragma unroll
    for (int qn = 0; qn < 2; qn++) {
        int q = q0 + w * 32 + qn * 16 + l16;
        #pragma unroll
        for (int dblk = 0; dblk < 2; dblk++) {
            f16x8 t = *(const f16x8*)(qk + (size_t)(b * T_SEQ + q) * 2048 +
                                      h * 64 + dblk * 32 + quad * 8);
            #pragma unroll
            for (int e = 0; e < 8; e++) t[e] = t[e] * (f16)0.125f;
            qf[qn][dblk] = t;
        }
    }

    float m_r[2] = {-INFINITY, -INFINITY};
    float l_r[2] = {0.0f, 0.0f};
    f32x4 Oacc[2][4] = {};

    for (int jt = 0; jt <= qt; jt++) {
        int j0 = jt * 128;
        __syncthreads();
        #pragma unroll
        for (int i = 0; i < 4; i++) {
            int L = i * 256 + tid;
            int j = L >> 3, g1 = L & 7;
            int g = g1 ^ (j & 7);
            async16((char*)Ks + (size_t)L * 16,
                    qk + (size_t)(b * T_SEQ + j0 + j) * 2048 + 1024 + h * 64 + g * 8);
        }
        #pragma unroll
        for (int i = 0; i < 4; i++) {
            int L = i * 256 + tid;
            int d = L >> 4, g1 = L & 15;
            int g = (g1 & 8) | ((g1 ^ d) & 7);
            async16((char*)Vs + (size_t)L * 16,
                    vT + ((size_t)(bh) * 64 + d) * 2048 + j0 + g * 8);
        }
        __syncthreads();

        // S^T = K . Q^T (pre-scaled)
        f32x4 S[8][2];
        #pragma unroll
        for (int jm = 0; jm < 8; jm++) {
            f16x8 kf[2];
            #pragma unroll
            for (int dblk = 0; dblk < 2; dblk++) {
                int j = jm * 16 + l16;
                int g = (dblk * 4 + quad) ^ (j & 7);
                kf[dblk] = *(const f16x8*)(Ks + (size_t)(j * 8 + g) * 8);
            }
            #pragma unroll
            for (int qn = 0; qn < 2; qn++) {
                f32x4 s = {};
                s = __builtin_amdgcn_mfma_f32_16x16x32_f16(kf[0], qf[qn][0], s, 0, 0, 0);
                s = __builtin_amdgcn_mfma_f32_16x16x32_f16(kf[1], qf[qn][1], s, 0, 0, 0);
                S[jm][qn] = s;
            }
        }

        if (jt == qt) {
            #pragma unroll
            for (int jm = 0; jm < 8; jm++)
                #pragma unroll
                for (int qn = 0; qn < 2; qn++)
                    #pragma unroll
                    for (int r = 0; r < 4; r++) {
                        int jl = jm * 16 + quad * 4 + r;
                        int ql = w * 32 + qn * 16 + l16;
                        if (jl > ql) S[jm][qn][r] = -1e30f;
                    }
        }

        float alpha[2];
        #pragma unroll
        for (int qn = 0; qn < 2; qn++) {
            float tmax = -INFINITY;
            #pragma unroll
            for (int jm = 0; jm < 8; jm++)
                #pragma unroll
                for (int r = 0; r < 4; r++)
                    tmax = fmaxf(tmax, S[jm][qn][r]);
            tmax = fmaxf(tmax, __shfl_xor(tmax, 16));
            tmax = fmaxf(tmax, __shfl_xor(tmax, 32));
            float mnew = fmaxf(m_r[qn], tmax);
            alpha[qn] = __expf(m_r[qn] - mnew);
            m_r[qn] = mnew;
            float rsum = 0.0f;
            #pragma unroll
            for (int jm = 0; jm < 8; jm++)
                #pragma unroll
                for (int r = 0; r < 4; r++) {
                    float p = __expf(S[jm][qn][r] - mnew);
                    S[jm][qn][r] = p;
                    rsum += p;
                }
            rsum += __shfl_xor(rsum, 16);
            rsum += __shfl_xor(rsum, 32);
            l_r[qn] = l_r[qn] * alpha[qn] + rsum;
        }

        #pragma unroll
        for (int jm = 0; jm < 8; jm++)
            #pragma unroll
            for (int qn = 0; qn < 2; qn++) {
                f16x4 pk;
                pk.x = (f16)S[jm][qn][0];
                pk.y = (f16)S[jm][qn][1];
                pk.z = (f16)S[jm][qn][2];
                pk.w = (f16)S[jm][qn][3];
                *(f16x4*)(Ps + (size_t)(qn * 16 + l16) * 136 + jm * 16 + quad * 4) = pk;
            }

        float aPV[2][4];
        #pragma unroll
        for (int m = 0; m < 2; m++)
            #pragma unroll
            for (int r = 0; r < 4; r++)
                aPV[m][r] = __shfl(alpha[m], quad * 20 + r);
        #pragma unroll
        for (int m = 0; m < 2; m++)
            #pragma unroll
            for (int n = 0; n < 4; n++)
                #pragma unroll
                for (int r = 0; r < 4; r++)
                    Oacc[m][n][r] *= aPV[m][r];

        #pragma unroll
        for (int kblk = 0; kblk < 4; kblk++) {
            f16x8 pf[2];
            #pragma unroll
            for (int m = 0; m < 2; m++)
                pf[m] = *(const f16x8*)(Ps + (size_t)(m * 16 + l16) * 136 +
                                        kblk * 32 + quad * 8);
            f16x8 vf[4];
            #pragma unroll
            for (int n = 0; n < 4; n++) {
                int d = n * 16 + l16;
                int g = (kblk * 4 + quad);
                int gs = (g & 8) | ((g ^ d) & 7);
                vf[n] = *(const f16x8*)(Vs + (size_t)(d * 16 + gs) * 8);
            }
            #pragma unroll
            for (int m = 0; m < 2; m++)
                #pragma unroll
                for (int n = 0; n < 4; n++)
                    Oacc[m][n] = __builtin_amdgcn_mfma_f32_16x16x32_f16(
                        pf[m], vf[n], Oacc[m][n], 0, 0, 0);
        }
    }

    #pragma unroll
    for (int m = 0; m < 2; m++) {
        float lPV[4];
        #pragma unroll
        for (int r = 0; r < 4; r++)
            lPV[r] = 1.0f / __shfl(l_r[m], quad * 20 + r);
        #pragma unroll
        for (int n = 0; n < 4; n++) {
            #pragma unroll
            for (int r = 0; r < 4; r++) {
                int q = q0 + w * 32 + m * 16 + quad * 4 + r;
                y[(size_t)(b * T_SEQ + q) * N_EMB + h * 64 + n * 16 + l16] =
                    (f16)(Oacc[m][n][r] * lPV[r]);
            }
        }
    }
}

// ---------------------------------------------------------------- launch
extern "C" void kernel_launch(void* const* d_in, const int* in_sizes, int n_in,
                              void* d_out, int out_size, void* d_ws, size_t ws_size,
                              hipStream_t stream) {
    const float* x      = (const float*)d_in[0];
    const float* ln1_g  = (const float*)d_in[1];
    const float* ln1_b  = (const float*)d_in[2];
    const float* w_attn = (const float*)d_in[3];
    const float* b_attn = (const float*)d_in[4];
    const float* w_proj = (const float*)d_in[5];
    const float* b_proj = (const float*)d_in[6];
    const float* ln2_g  = (const float*)d_in[7];
    const float* ln2_b  = (const float*)d_in[8];
    const float* w_fc   = (const float*)d_in[9];
    const float* b_fc   = (const float*)d_in[10];
    const float* w_fc2  = (const float*)d_in[11];
    const float* b_fc2  = (const float*)d_in[12];
    float* out = (float*)d_out;

    const size_t MB = 1024 * 1024;
    char* ws = (char*)d_ws;
    f16*   lnbuf = (f16*)ws;                        // 16 MB
    f16*   qkbuf = (f16*)(ws + 16 * MB);            // 32 MB: [M][2048] Q|K
    f16*   vTbuf = (f16*)(ws + 48 * MB);            // 16 MB: [b][h][d][t]
    f16*   ybuf  = (f16*)(ws + 64 * MB);            // 16 MB
    f16*   h     = (f16*)(ws + 80 * MB);            // 64 MB
    f16*   wT    = (f16*)(ws + 144 * MB);           // 26 MB
    f16* wT_attn = wT;
    f16* wT_proj = wT_attn + (size_t)3072 * 1024;
    f16* wT_fc   = wT_proj + (size_t)1024 * 1024;
    f16* wT_fc2  = wT_fc   + (size_t)1024 * 4096;

    wconv_kernel<<<dim3(3072 / 32, 1024 / 32), 256, 0, stream>>>(w_attn, wT_attn, 1024, 3072);
    wconv_kernel<<<dim3(1024 / 32, 1024 / 32), 256, 0, stream>>>(w_proj, wT_proj, 1024, 1024);
    wconv_kernel<<<dim3(4096 / 32, 1024 / 32), 256, 0, stream>>>(w_fc,   wT_fc,   1024, 4096);
    wconv_kernel<<<dim3(1024 / 32, 4096 / 32), 256, 0, stream>>>(w_fc2,  wT_fc2,  4096, 1024);

    ln_kernel<<<M_ROWS, 256, 0, stream>>>(x, ln1_g, ln1_b, lnbuf);
    gemm_f16<3><<<dim3(3072 / 128, M_ROWS / 128), 256, 0, stream>>>(
        lnbuf, wT_attn, b_attn, nullptr, nullptr, qkbuf, vTbuf, 1024, 3072);
    flash_kernel<<<dim3(16, 64), 256, 0, stream>>>(qkbuf, vTbuf, ybuf);
    gemm_f16<1><<<dim3(1024 / 128, M_ROWS / 128), 256, 0, stream>>>(
        ybuf, wT_proj, b_proj, x, out, nullptr, nullptr, 1024, 1024);
    ln_kernel<<<M_ROWS, 256, 0, stream>>>(out, ln2_g, ln2_b, lnbuf);
    gemm_f16<2><<<dim3(4096 / 128, M_ROWS / 128), 256, 0, stream>>>(
        lnbuf, wT_fc, b_fc, nullptr, nullptr, h, nullptr, 1024, 4096);
    gemm_f16<1><<<dim3(1024 / 128, M_ROWS / 128), 256, 0, stream>>>(
        h, wT_fc2, b_fc2, out, out, nullptr, nullptr, 4096, 1024);
}